// Round 2
// baseline (9119.193 us; speedup 1.0000x reference)
//
#include <hip/hip_runtime.h>

// ---------------------------------------------------------------------------
// 4-layer tanh RNN, T=256, B=128, H=1024 (fp32 in/out), MI355X gfx950.
//
// Round 4 changes vs round 3 (8654 us, MfmaUtil 2.5%, 2.1 TB/s through L3):
//  * Root cause: every block of a layer reads the identical 512 KB A-operand
//    each step (72 MB/step), and the per-step agent acquire fence (buffer_inv,
//    executed ~16x/XCD/step by staggered blocks) destroyed all XCD-L2 sharing,
//    forcing the whole broadcast through L3/fabric at ~2.1 TB/s = 33 us/step.
//  * Fix: FULL-T activation buffer (L*T*B*H bf16 = 256 MB workspace). Ring
//    addresses are never reused -> a consumer's L1/L2 can never hold a stale
//    copy (lines are only ever read after the producer's flag, and written
//    exactly once via agent write-through to L3). So: NO fences at all, plain
//    cached loads, and same-layer blocks on an XCD share one L3->L2 fill per
//    line. L3 traffic drops ~4.5x; fence/refetch latency leaves the critical
//    path.
//  * Fallback if ws is small: power-of-2 ring with ONE acquire fence every
//    `slots` steps (correct: between two reads of the same slot address there
//    is exactly one fence, and no stale refill can occur in between because a
//    slot is only read at its own step).
// ---------------------------------------------------------------------------

#define TT 256
#define BB 128
#define HH 1024
#define LL 4
#define MAT (BB * HH)          // 131072 elements per [B,H] matrix

typedef __attribute__((ext_vector_type(4))) float  float4v;
typedef __attribute__((ext_vector_type(8))) __bf16 bf16x8;
typedef __attribute__((ext_vector_type(8))) unsigned short ushort8;

__device__ inline unsigned short bf16r(float f) {
    union { float f; unsigned u; } v; v.f = f;
    unsigned u = v.u;
    u += 0x7fffu + ((u >> 16) & 1u);     // round-to-nearest-even
    return (unsigned short)(u >> 16);
}

__device__ inline bf16x8 pack8(float4v a, float4v b) {
    ushort8 r;
    r[0] = bf16r(a[0]); r[1] = bf16r(a[1]); r[2] = bf16r(a[2]); r[3] = bf16r(a[3]);
    r[4] = bf16r(b[0]); r[5] = bf16r(b[1]); r[6] = bf16r(b[2]); r[7] = bf16r(b[3]);
    return __builtin_bit_cast(bf16x8, r);
}

__device__ inline float4v mfma16(bf16x8 a, bf16x8 b, float4v c) {
    return __builtin_amdgcn_mfma_f32_16x16x32_bf16(a, b, c, 0, 0, 0);
}

__device__ inline float fast_tanh(float x) {
    float ax = fabsf(x);
    float e  = __expf(-2.0f * ax);
    float r  = (1.0f - e) / (1.0f + e);
    return copysignf(r, x);
}

// --------------------------- prep: flags + h init ---------------------------
__global__ void rnn_prep(const float* __restrict__ hxs,
                         unsigned* __restrict__ F,
                         unsigned short* __restrict__ ring,
                         int slots) {
    int i = blockIdx.x * blockDim.x + threadIdx.x;
    if (i < 256) F[i] = 0u;              // counters live at F[g*64], g=0..3
    int stride = gridDim.x * blockDim.x;
    for (int idx = i; idx < LL * MAT; idx += stride) {
        int g = idx >> 17;               // / MAT
        int rem = idx & (MAT - 1);
        // initial h for layer g -> slot slots-1 (read at t=0 as (t-1)%slots)
        ring[((size_t)g * slots + (slots - 1)) * MAT + rem] = bf16r(hxs[idx]);
    }
    // end-of-kernel implicit release flushes these to the coherence point
}

// --------------------------- main pipelined kernel --------------------------
__global__ __launch_bounds__(512, 2) void rnn_pipeline(
    const float* __restrict__ xin,   // [T][B][H] fp32
    const float* __restrict__ Wih,   // [L][H][H]
    const float* __restrict__ bih,   // [L][H]
    const float* __restrict__ Whh,   // [L][H][H]
    const float* __restrict__ bhh,   // [L][H]
    float* __restrict__ out,         // [T*B*H + L*B*H]
    unsigned* __restrict__ F,        // counters: F[g*64] = 32*(steps done)
    unsigned short* __restrict__ ring, // [L][slots][B*H] bf16
    int slots)
{
    const int tid  = threadIdx.x;
    const int lane = tid & 63;
    const int wid  = tid >> 6;       // 0..7
    const int ks   = wid & 3;        // K-slice: 0,1 = x-half; 2,3 = h-half
    const int mh   = wid >> 2;       // m-half (64 rows)
    const int g    = blockIdx.x >> 5;  // layer
    const int nt   = blockIdx.x & 31;  // n-tile
    const int n0   = nt * 32;
    const int smask = slots - 1;
    const bool may_fence = (slots < TT);   // full-T buffer never needs fences

    __shared__ float4v lds_part[8 * 4 * 2 * 64];   // [wid][mt][nt2][lane] = 64KB

    const int rA = lane & 15;        // fragment row/col within tile
    const int qA = lane >> 4;        // quad -> k offset *8

    // ---- load weight fragments into registers (once) ----
    // wfrag[nt2][ki]: lane&15 = n-row (within 16), 8 k-elements. Used as the
    // MFMA A-operand (so D rows = n, D cols = m -> n contiguous in regs).
    bf16x8 wfrag[2][16];
    {
        const float* Wsrc = (ks < 2) ? (Wih + (size_t)g * HH * HH)
                                     : (Whh + (size_t)g * HH * HH);
        const int kofs = (ks & 1) * 512;
        #pragma unroll
        for (int nt2 = 0; nt2 < 2; ++nt2) {
            const int n = n0 + nt2 * 16 + rA;
            const float* rowp = Wsrc + (size_t)n * HH + kofs + qA * 8;
            #pragma unroll
            for (int ki = 0; ki < 16; ++ki) {
                float4v f0 = *(const float4v*)(rowp + ki * 32);
                float4v f1 = *(const float4v*)(rowp + ki * 32 + 4);
                wfrag[nt2][ki] = pack8(f0, f1);
            }
        }
    }

    // ---- reduce-phase constants ----
    const int rest0 = tid >> 6;
    const int nt2r  = rest0 & 1;
    const int mtr   = (rest0 >> 1) & 3;
    const int l2    = lane;
    const int n4    = l2 & 3;            // which n-quad within 16
    const int mi    = l2 >> 2;           // m within 16
    const int lidx  = n4 * 16 + mi;      // LDS lane slot holding (mi, n4)
    const int nbase = n0 + nt2r * 16 + n4 * 4;
    float4v biasv;
    {
        float4v bi = *(const float4v*)(bih + (size_t)g * HH + nbase);
        float4v bh = *(const float4v*)(bhh + (size_t)g * HH + nbase);
        biasv = bi + bh;
    }

    // ---- A-operand lane offset (element units within a [B,H] matrix) ----
    const int aoff = (mh * 64 + rA) * HH + (ks & 1) * 512 + qA * 8;
    const bool is_x = (ks < 2);

    const unsigned short* ringL = ring + (size_t)g * slots * MAT;
    const unsigned short* ringP = (g > 0) ? ring + (size_t)(g - 1) * slots * MAT
                                          : (const unsigned short*)0;
    unsigned short* ringM = ring + (size_t)g * slots * MAT;

    for (int t = 0; t < TT; ++t) {
        // -------- wait for dependencies (wave 0 polls up to 3 counters) -----
        if (wid == 0) {
            int fidx = g; unsigned tgt = 0u; bool act = false;
            if (lane == 0) {                       // own layer h_{t-1} complete
                act = true; tgt = 32u * (unsigned)t;
            } else if (lane == 1 && g > 0) {       // prev layer produced x_t
                act = true; fidx = g - 1; tgt = 32u * (unsigned)(t + 1);
            } else if (lane == 2 && g < 3 && t >= slots) {  // slot reuse guard
                act = true; fidx = g + 1; tgt = 32u * (unsigned)(t - slots + 1);
            }
            for (;;) {
                bool ok = true;
                if (act) {
                    unsigned v = __hip_atomic_load(F + fidx * 64,
                                     __ATOMIC_RELAXED, __HIP_MEMORY_SCOPE_AGENT);
                    ok = (v >= tgt);
                }
                if (__ballot(!ok) == 0ull) break;
                __builtin_amdgcn_s_sleep(1);
            }
            // Fences only in the small-workspace fallback, once per slot
            // cycle. Full-T path: addresses are write-once, read-after-flag,
            // so caches can never be stale and no fence is needed.
            if (may_fence && (t & smask) == 0)
                __builtin_amdgcn_fence(__ATOMIC_ACQUIRE, "agent");
        }
        __syncthreads();

        // -------- fused GEMM over this wave's K-slice --------
        float4v acc[4][2];
        #pragma unroll
        for (int mt = 0; mt < 4; ++mt) {
            acc[mt][0] = (float4v)0.0f;
            acc[mt][1] = (float4v)0.0f;
        }

        if (is_x && g == 0) {
            // layer-0 x half: plain cached fp32 loads from xin + pack
            const float* xsrc = xin + (size_t)t * MAT;
            #pragma unroll
            for (int ki = 0; ki < 16; ++ki) {
                #pragma unroll
                for (int mt = 0; mt < 4; ++mt) {
                    const float* p = xsrc + aoff + mt * (16 * HH) + ki * 32;
                    float4v f0 = *(const float4v*)p;
                    float4v f1 = *(const float4v*)(p + 4);
                    bf16x8 a = pack8(f0, f1);
                    acc[mt][0] = mfma16(wfrag[0][ki], a, acc[mt][0]);
                    acc[mt][1] = mfma16(wfrag[1][ki], a, acc[mt][1]);
                }
            }
        } else {
            // ring-sourced half: plain cached bf16x8 loads. Lines are fresh
            // by construction (write-once addresses in the full-T path);
            // same-layer blocks on this XCD share the L2 copy.
            const unsigned short* asrc =
                is_x ? (ringP + (size_t)(t & smask) * MAT)
                     : (ringL + (size_t)((t + slots - 1) & smask) * MAT);
            const unsigned short* ap = asrc + aoff;
            #pragma unroll
            for (int ki = 0; ki < 16; ++ki) {
                #pragma unroll
                for (int mt = 0; mt < 4; ++mt) {
                    bf16x8 a = *(const bf16x8*)(ap + mt * (16 * HH) + ki * 32);
                    acc[mt][0] = mfma16(wfrag[0][ki], a, acc[mt][0]);
                    acc[mt][1] = mfma16(wfrag[1][ki], a, acc[mt][1]);
                }
            }
        }

        // -------- partials -> LDS --------
        #pragma unroll
        for (int mt = 0; mt < 4; ++mt)
            #pragma unroll
            for (int nt2 = 0; nt2 < 2; ++nt2)
                lds_part[((wid * 4 + mt) * 2 + nt2) * 64 + lane] = acc[mt][nt2];
        __syncthreads();

        // -------- reduce 4 K-slices + bias + tanh + packed stores --------
        unsigned short* ringW = ringM + (size_t)(t & smask) * MAT;
        #pragma unroll
        for (int s = 0; s < 2; ++s) {           // s = m-half
            float4v sum = lds_part[(((s * 4 + 0) * 4 + mtr) * 2 + nt2r) * 64 + lidx];
            #pragma unroll
            for (int k2 = 1; k2 < 4; ++k2)
                sum += lds_part[(((s * 4 + k2) * 4 + mtr) * 2 + nt2r) * 64 + lidx];
            sum += biasv;
            float vals[4];
            #pragma unroll
            for (int r = 0; r < 4; ++r) vals[r] = fast_tanh(sum[r]);

            const int m = s * 64 + mtr * 16 + mi;
            const size_t eo = (size_t)m * HH + nbase;

            // ring publish: one packed 8B relaxed agent store (write-through
            // to the coherence point; never cached dirty in local L2)
            union { unsigned short us[4]; unsigned long long u; } pk;
            #pragma unroll
            for (int r = 0; r < 4; ++r) pk.us[r] = bf16r(vals[r]);
            __hip_atomic_store((unsigned long long*)(ringW + eo), pk.u,
                               __ATOMIC_RELAXED, __HIP_MEMORY_SCOPE_AGENT);

            if (g == 3) {
                float4v o;
                #pragma unroll
                for (int r = 0; r < 4; ++r) o[r] = vals[r];
                *(float4v*)(out + (size_t)t * MAT + eo) = o;
            }
            if (t == TT - 1) {
                float4v o;
                #pragma unroll
                for (int r = 0; r < 4; ++r) o[r] = vals[r];
                *(float4v*)(out + (size_t)TT * MAT + (size_t)g * MAT + eo) = o;
            }
        }

        // -------- publish progress --------
        // Drain this wave's ring stores to the coherence point, then barrier
        // (all waves drained), then one relaxed counter bump per block.
        asm volatile("s_waitcnt vmcnt(0)" ::: "memory");
        __syncthreads();
        if (tid == 0)
            __hip_atomic_fetch_add(F + g * 64, 1u,
                                   __ATOMIC_RELAXED, __HIP_MEMORY_SCOPE_AGENT);
    }
}

// ------------------------------- launcher -----------------------------------
extern "C" void kernel_launch(void* const* d_in, const int* in_sizes, int n_in,
                              void* d_out, int out_size, void* d_ws, size_t ws_size,
                              hipStream_t stream) {
    const float* xin = (const float*)d_in[0];
    const float* hxs = (const float*)d_in[1];
    const float* Wih = (const float*)d_in[2];
    const float* bih = (const float*)d_in[3];
    const float* Whh = (const float*)d_in[4];
    const float* bhh = (const float*)d_in[5];
    float* out = (float*)d_out;

    unsigned* F = (unsigned*)d_ws;
    unsigned short* ring = (unsigned short*)((char*)d_ws + 4096);

    // Pick the largest power-of-2 slot count that fits the workspace, capped
    // at T (=256: full trace, write-once addresses, fence-free).
    int slots = 8;
    while (slots < TT) {
        size_t need = 4096 + (size_t)LL * (size_t)(slots * 2) * (size_t)MAT * 2ull;
        if (need <= ws_size) slots *= 2; else break;
    }
    // ws usage at slots=256: 4KB + 4*256*131072*2B = 256 MB + 4 KB

    rnn_prep<<<256, 256, 0, stream>>>(hxs, F, ring, slots);
    rnn_pipeline<<<128, 512, 0, stream>>>(xin, Wih, bih, Whh, bhh, out, F, ring, slots);
}

// Round 3
// 7210.160 us; speedup vs baseline: 1.2648x; 1.2648x over previous
//
#include <hip/hip_runtime.h>

// ---------------------------------------------------------------------------
// 4-layer tanh RNN, T=256, B=128, H=1024 (fp32 in/out), MI355X gfx950.
//
// Round 5 changes vs round 4 (8955 us; protocol changes r2->r4 all flat =>
// bottleneck is the per-step critical-path composition, not coherence):
//  * X-projection (x_t @ Wih^T) moved OFF the h-recurrence critical path:
//    computed for step t+1 AFTER publishing h_t (overlaps the 32-block flag
//    wait), held block-locally in LDS as fp32 (18 KB). No global round trip,
//    no flags (producer == consumer block).
//  * On-path GEMM halved: only h_{t-1} @ Whh^T, all 8 waves split K=1024
//    (32 loads + 64 MFMAs per wave on the pacing chain, was 64+128 combined,
//    plus fp32->bf16 pack for layer 0).
//  * Contended atomicAdd counter (32 serialized RMWs/step at one address)
//    replaced by per-block owned flag (relaxed 4B store) + 32-lane gather
//    poll (round-2 style detection, the fastest measured variant).
//  * Kept: full-T write-once ring (fence-free), packed 8B publishes,
//    drain-before-flag, register-resident weights.
// ---------------------------------------------------------------------------

#define TT 256
#define BB 128
#define HH 1024
#define LL 4
#define MAT (BB * HH)          // 131072 elements per [B,H] matrix

typedef __attribute__((ext_vector_type(4))) float  float4v;
typedef __attribute__((ext_vector_type(8))) __bf16 bf16x8;
typedef __attribute__((ext_vector_type(8))) unsigned short ushort8;

__device__ inline unsigned short bf16r(float f) {
    union { float f; unsigned u; } v; v.f = f;
    unsigned u = v.u;
    u += 0x7fffu + ((u >> 16) & 1u);     // round-to-nearest-even
    return (unsigned short)(u >> 16);
}

__device__ inline bf16x8 pack8(float4v a, float4v b) {
    ushort8 r;
    r[0] = bf16r(a[0]); r[1] = bf16r(a[1]); r[2] = bf16r(a[2]); r[3] = bf16r(a[3]);
    r[4] = bf16r(b[0]); r[5] = bf16r(b[1]); r[6] = bf16r(b[2]); r[7] = bf16r(b[3]);
    return __builtin_bit_cast(bf16x8, r);
}

__device__ inline float4v mfma16(bf16x8 a, bf16x8 b, float4v c) {
    return __builtin_amdgcn_mfma_f32_16x16x32_bf16(a, b, c, 0, 0, 0);
}

__device__ inline float fast_tanh(float x) {
    float ax = fabsf(x);
    float e  = __expf(-2.0f * ax);
    float r  = (1.0f - e) / (1.0f + e);
    return copysignf(r, x);
}

// --------------------------- prep: flags + h init ---------------------------
__global__ void rnn_prep(const float* __restrict__ hxs,
                         unsigned* __restrict__ F,
                         unsigned short* __restrict__ ring,
                         int slots) {
    int i = blockIdx.x * blockDim.x + threadIdx.x;
    if (i < 256) F[i] = 0u;              // per-block flags at F[g*32+nt]
    int stride = gridDim.x * blockDim.x;
    for (int idx = i; idx < LL * MAT; idx += stride) {
        int g = idx >> 17;               // / MAT
        int rem = idx & (MAT - 1);
        // initial h for layer g -> slot slots-1 (read at t=0 as (t-1)%slots)
        ring[((size_t)g * slots + (slots - 1)) * MAT + rem] = bf16r(hxs[idx]);
    }
}

// --------------------------- main pipelined kernel --------------------------
__global__ __launch_bounds__(512, 2) void rnn_pipeline(
    const float* __restrict__ xin,   // [T][B][H] fp32
    const float* __restrict__ Wih,   // [L][H][H]
    const float* __restrict__ bih,   // [L][H]
    const float* __restrict__ Whh,   // [L][H][H]
    const float* __restrict__ bhh,   // [L][H]
    float* __restrict__ out,         // [T*B*H + L*B*H]
    unsigned* __restrict__ F,        // flags: F[g*32+nt] = steps completed
    unsigned short* __restrict__ ring, // [L][slots][B*H] bf16
    int slots)
{
    const int tid  = threadIdx.x;
    const int lane = tid & 63;
    const int wid  = tid >> 6;         // 0..7
    const int ks   = wid & 3;          // K-quarter (256 wide) of each matrix
    const int mh   = wid >> 2;         // m-half (64 rows)
    const int g    = blockIdx.x >> 5;  // layer
    const int nt   = blockIdx.x & 31;  // n-tile
    const int n0   = nt * 32;
    const int smask = slots - 1;
    const bool may_fence = (slots < TT);

    __shared__ float4v lds_part[8 * 4 * 2 * 64];               // 64 KB
    __shared__ __attribute__((aligned(16))) float X_lds[BB * 36]; // 18 KB

    const int rA = lane & 15;
    const int qA = lane >> 4;

    // ---- weight fragments: K=256 slice of BOTH matrices per wave ----
    bf16x8 wh[2][8], wx[2][8];
    {
        const float* Hsrc = Whh + (size_t)g * HH * HH;
        const float* Xsrc = Wih + (size_t)g * HH * HH;
        const int kofs = ks * 256;
        #pragma unroll
        for (int nt2 = 0; nt2 < 2; ++nt2) {
            const int n = n0 + nt2 * 16 + rA;
            const float* hp = Hsrc + (size_t)n * HH + kofs + qA * 8;
            const float* xp = Xsrc + (size_t)n * HH + kofs + qA * 8;
            #pragma unroll
            for (int ki = 0; ki < 8; ++ki) {
                wh[nt2][ki] = pack8(*(const float4v*)(hp + ki * 32),
                                    *(const float4v*)(hp + ki * 32 + 4));
                wx[nt2][ki] = pack8(*(const float4v*)(xp + ki * 32),
                                    *(const float4v*)(xp + ki * 32 + 4));
            }
        }
    }

    // ---- reduce-phase constants (wave wid owns (nt2r, mtr) slice) ----
    const int nt2r  = wid & 1;
    const int mtr   = (wid >> 1) & 3;
    const int n4    = lane & 3;
    const int mi    = lane >> 2;
    const int lidx  = n4 * 16 + mi;
    const int xcol  = nt2r * 16 + n4 * 4;      // col within block's 32
    const int nbase = n0 + xcol;
    float4v biasv;
    {
        float4v bi = *(const float4v*)(bih + (size_t)g * HH + nbase);
        float4v bh = *(const float4v*)(bhh + (size_t)g * HH + nbase);
        biasv = bi + bh;
    }

    // ---- A-operand lane offset ----
    const int aoff = (mh * 64 + rA) * HH + ks * 256 + qA * 8;

    const unsigned short* ringL = ring + (size_t)g * slots * MAT;
    const unsigned short* ringP = (g > 0) ? ring + (size_t)(g - 1) * slots * MAT
                                          : (const unsigned short*)0;
    unsigned short* ringM = ring + (size_t)g * slots * MAT;

    // X-phase: GEMM for time u against Wih slice, reduce into X_lds (fp32).
    // Preceding code guarantees lds_part is free and prev data is published.
#define XPHASE(u)                                                             \
    {                                                                         \
        float4v accx[4][2];                                                   \
        _Pragma("unroll")                                                     \
        for (int mt = 0; mt < 4; ++mt) {                                      \
            accx[mt][0] = (float4v)0.0f; accx[mt][1] = (float4v)0.0f;         \
        }                                                                     \
        if (g == 0) {                                                         \
            const float* xsrc = xin + (size_t)(u) * MAT + aoff;               \
            _Pragma("unroll")                                                 \
            for (int ki = 0; ki < 8; ++ki) {                                  \
                _Pragma("unroll")                                             \
                for (int mt = 0; mt < 4; ++mt) {                              \
                    const float* p = xsrc + mt * (16 * HH) + ki * 32;         \
                    bf16x8 a = pack8(*(const float4v*)p,                      \
                                     *(const float4v*)(p + 4));               \
                    accx[mt][0] = mfma16(wx[0][ki], a, accx[mt][0]);          \
                    accx[mt][1] = mfma16(wx[1][ki], a, accx[mt][1]);          \
                }                                                             \
            }                                                                 \
        } else {                                                              \
            const unsigned short* ap =                                        \
                ringP + (size_t)((u) & smask) * MAT + aoff;                   \
            _Pragma("unroll")                                                 \
            for (int ki = 0; ki < 8; ++ki) {                                  \
                _Pragma("unroll")                                             \
                for (int mt = 0; mt < 4; ++mt) {                              \
                    bf16x8 a = *(const bf16x8*)(ap + mt * (16 * HH) + ki * 32); \
                    accx[mt][0] = mfma16(wx[0][ki], a, accx[mt][0]);          \
                    accx[mt][1] = mfma16(wx[1][ki], a, accx[mt][1]);          \
                }                                                             \
            }                                                                 \
        }                                                                     \
        _Pragma("unroll")                                                     \
        for (int mt = 0; mt < 4; ++mt)                                        \
            _Pragma("unroll")                                                 \
            for (int nt2 = 0; nt2 < 2; ++nt2)                                 \
                lds_part[((wid * 4 + mt) * 2 + nt2) * 64 + lane] = accx[mt][nt2]; \
        __syncthreads();                                                      \
        _Pragma("unroll")                                                     \
        for (int s = 0; s < 2; ++s) {                                         \
            float4v sum = lds_part[(((s*4+0)*4+mtr)*2+nt2r)*64 + lidx];       \
            _Pragma("unroll")                                                 \
            for (int k2 = 1; k2 < 4; ++k2)                                    \
                sum += lds_part[(((s*4+k2)*4+mtr)*2+nt2r)*64 + lidx];         \
            const int m = s * 64 + mtr * 16 + mi;                             \
            *(float4v*)(&X_lds[m * 36 + xcol]) = sum;                         \
        }                                                                     \
    }

    // -------- prologue: X for t=0 --------
    if (g > 0) {
        // wave-local poll: prev layer completed step 0
        for (;;) {
            bool ok = true;
            if (lane < 32)
                ok = (__hip_atomic_load(F + (g - 1) * 32 + lane,
                          __ATOMIC_RELAXED, __HIP_MEMORY_SCOPE_AGENT) >= 1u);
            if (__ballot(!ok) == 0ull) break;
            __builtin_amdgcn_s_sleep(1);
        }
    }
    XPHASE(0)
    // X_lds read is separated from this write by the loop-top barrier.

    for (int t = 0; t < TT; ++t) {
        // -------- own-h wait: wid0 polls 32 per-block flags --------
        if (wid == 0) {
            const unsigned tgt = (unsigned)t;
            const bool actA = (lane < 32);
            const bool actB = may_fence && (lane >= 32) && (g < 3) && (t >= slots);
            const unsigned tgtb = (unsigned)(t - slots + 1);
            for (;;) {
                bool ok = true;
                if (actA)
                    ok = (__hip_atomic_load(F + g * 32 + lane,
                              __ATOMIC_RELAXED, __HIP_MEMORY_SCOPE_AGENT) >= tgt);
                else if (actB)
                    ok = (__hip_atomic_load(F + (g + 1) * 32 + (lane - 32),
                              __ATOMIC_RELAXED, __HIP_MEMORY_SCOPE_AGENT) >= tgtb);
                if (__ballot(!ok) == 0ull) break;
                __builtin_amdgcn_s_sleep(1);
            }
            if (may_fence && (t & smask) == 0)
                __builtin_amdgcn_fence(__ATOMIC_ACQUIRE, "agent");
        }
        __syncthreads();

        // -------- critical GEMM: h_{t-1} @ Whh^T (K=256 per wave) --------
        float4v acc[4][2];
        #pragma unroll
        for (int mt = 0; mt < 4; ++mt) {
            acc[mt][0] = (float4v)0.0f;
            acc[mt][1] = (float4v)0.0f;
        }
        {
            const unsigned short* ap =
                ringL + (size_t)((t + slots - 1) & smask) * MAT + aoff;
            #pragma unroll
            for (int ki = 0; ki < 8; ++ki) {
                #pragma unroll
                for (int mt = 0; mt < 4; ++mt) {
                    bf16x8 a = *(const bf16x8*)(ap + mt * (16 * HH) + ki * 32);
                    acc[mt][0] = mfma16(wh[0][ki], a, acc[mt][0]);
                    acc[mt][1] = mfma16(wh[1][ki], a, acc[mt][1]);
                }
            }
        }

        #pragma unroll
        for (int mt = 0; mt < 4; ++mt)
            #pragma unroll
            for (int nt2 = 0; nt2 < 2; ++nt2)
                lds_part[((wid * 4 + mt) * 2 + nt2) * 64 + lane] = acc[mt][nt2];
        __syncthreads();

        // -------- reduce + X + bias + tanh + publish --------
        unsigned short* ringW = ringM + (size_t)(t & smask) * MAT;
        #pragma unroll
        for (int s = 0; s < 2; ++s) {
            float4v sum = lds_part[(((s*4+0)*4+mtr)*2+nt2r)*64 + lidx];
            #pragma unroll
            for (int k2 = 1; k2 < 4; ++k2)
                sum += lds_part[(((s*4+k2)*4+mtr)*2+nt2r)*64 + lidx];
            const int m = s * 64 + mtr * 16 + mi;
            sum += *(const float4v*)(&X_lds[m * 36 + xcol]);
            sum += biasv;
            float vals[4];
            #pragma unroll
            for (int r = 0; r < 4; ++r) vals[r] = fast_tanh(sum[r]);

            const size_t eo = (size_t)m * HH + nbase;
            union { unsigned short us[4]; unsigned long long u; } pk;
            #pragma unroll
            for (int r = 0; r < 4; ++r) pk.us[r] = bf16r(vals[r]);
            __hip_atomic_store((unsigned long long*)(ringW + eo), pk.u,
                               __ATOMIC_RELAXED, __HIP_MEMORY_SCOPE_AGENT);

            if (g == 3) {
                float4v o;
                #pragma unroll
                for (int r = 0; r < 4; ++r) o[r] = vals[r];
                *(float4v*)(out + (size_t)t * MAT + eo) = o;
            }
            if (t == TT - 1) {
                float4v o;
                #pragma unroll
                for (int r = 0; r < 4; ++r) o[r] = vals[r];
                *(float4v*)(out + (size_t)TT * MAT + (size_t)g * MAT + eo) = o;
            }
        }

        // -------- drain + publish own flag (no RMW) --------
        asm volatile("s_waitcnt vmcnt(0)" ::: "memory");
        __syncthreads();
        if (tid == 0)
            __hip_atomic_store(F + g * 32 + nt, (unsigned)(t + 1),
                               __ATOMIC_RELAXED, __HIP_MEMORY_SCOPE_AGENT);

        // -------- X for step t+1 (overlaps other blocks' flag wait) --------
        if (t < TT - 1) {
            const int u = t + 1;
            if (g > 0) {
                const unsigned tgt = (unsigned)(u + 1);
                for (;;) {
                    bool ok = true;
                    if (lane < 32)
                        ok = (__hip_atomic_load(F + (g - 1) * 32 + lane,
                                  __ATOMIC_RELAXED, __HIP_MEMORY_SCOPE_AGENT) >= tgt);
                    if (__ballot(!ok) == 0ull) break;
                    __builtin_amdgcn_s_sleep(1);
                }
            }
            if (may_fence && ((u & smask) == 0))
                __builtin_amdgcn_fence(__ATOMIC_ACQUIRE, "agent");
            XPHASE(u)
        }
    }
#undef XPHASE
}

// ------------------------------- launcher -----------------------------------
extern "C" void kernel_launch(void* const* d_in, const int* in_sizes, int n_in,
                              void* d_out, int out_size, void* d_ws, size_t ws_size,
                              hipStream_t stream) {
    const float* xin = (const float*)d_in[0];
    const float* hxs = (const float*)d_in[1];
    const float* Wih = (const float*)d_in[2];
    const float* bih = (const float*)d_in[3];
    const float* Whh = (const float*)d_in[4];
    const float* bhh = (const float*)d_in[5];
    float* out = (float*)d_out;

    unsigned* F = (unsigned*)d_ws;
    unsigned short* ring = (unsigned short*)((char*)d_ws + 4096);

    // Largest power-of-2 slot count that fits, capped at T (=256: write-once
    // addresses, fence-free).
    int slots = 8;
    while (slots < TT) {
        size_t need = 4096 + (size_t)LL * (size_t)(slots * 2) * (size_t)MAT * 2ull;
        if (need <= ws_size) slots *= 2; else break;
    }

    rnn_prep<<<256, 256, 0, stream>>>(hxs, F, ring, slots);
    rnn_pipeline<<<128, 512, 0, stream>>>(xin, Wih, bih, Whh, bhh, out, F, ring, slots);
}